// Round 2
// 443.276 us; speedup vs baseline: 1.1491x; 1.1491x over previous
//
#include <hip/hip_runtime.h>

#define S_LEN  2048
#define BATCH  1024
#define NL     6
#define CH     16      // timesteps per chunk (x-prefetch granularity)

typedef float f32x2 __attribute__((ext_vector_type(2)));

__device__ __forceinline__ float fexp2(float x) { return __builtin_amdgcn_exp2f(x); }
__device__ __forceinline__ float frcp(float x)  { return __builtin_amdgcn_rcpf(x); }

// quad_perm DPP: xor1=[1,0,3,2]=0xB1, xor2=[2,3,0,1]=0x4E, xor3=[3,2,1,0]=0x1B
template <int CTRL>
__device__ __forceinline__ float dppf(float v) {
    return __int_as_float(__builtin_amdgcn_update_dpp(
        0, __float_as_int(v), CTRL, 0xF, 0xF, true));
}
__device__ __forceinline__ float bpermf(int addr, float v) {
    return __int_as_float(__builtin_amdgcn_ds_bpermute(addr, __float_as_int(v)));
}
// packed fp32 fma: d.lo = a.lo*b.lo + c.lo ; d.hi = a.hi*b.hi + c.hi
__device__ __forceinline__ f32x2 pkfma(f32x2 a, f32x2 b, f32x2 c) {
    f32x2 d;
    asm("v_pk_fma_f32 %0, %1, %2, %3" : "=v"(d) : "v"(a), "v"(b), "v"(c));
    return d;
}

// ONE wave carries the whole 6-layer pipeline for 2 batch elements.
// lane = L*8 + e*4 + j. Lanes 56-63 are feeders publishing x[t] via hsrc.
// Per step: 1 bpermute + 6 DPP + 16 v_pk_fma_f32 (lo=Wh-chain, hi=Wx-chain,
// weights pre-scaled by -log2e / -2log2e so exp2 args come out directly).
// Masking exists only in chunk 0 (pipeline fill); bulk chunks are maskless.
__global__ __launch_bounds__(64, 1) void lstm_wavepipe(
    const float* __restrict__ x, const float* __restrict__ w_ih,
    const float* __restrict__ w_hh, const float* __restrict__ b_ih,
    const float* __restrict__ b_hh, const float* __restrict__ reg_w,
    const float* __restrict__ reg_b, float* __restrict__ out) {
    const int lane = threadIdx.x;
    const int L    = lane >> 3;
    const int e    = (lane >> 2) & 1;
    const int j    = lane & 3;
    const int b    = blockIdx.x * 2 + e;
    const int Lc   = (L < NL) ? L : NL - 1;      // clamp for safe weight loads
    const bool isFeeder = (lane >= 56);
    const bool isOut    = (L == 5) && (j == 0);

    const float KGc = -2.885390082f;             // -2*log2(e)
    const float KIc = -1.442695041f;             // -log2(e)

    // ---- weight preload: packed {Wh, Wx}, pre-scaled; term m = unit j^m ----
    f32x2 WP[4][4], GbP[4];
#pragma unroll
    for (int g = 0; g < 4; ++g) {
        const float kk = (g == 2) ? KGc : KIc;
        const int row = Lc * 16 + g * 4 + j;     // PyTorch gate order i,f,g,o
#pragma unroll
        for (int m = 0; m < 4; ++m) {
            f32x2 w;
            w.x = w_hh[row * 4 + (j ^ m)] * kk;  // lo lane: recurrent chain
            w.y = w_ih[row * 4 + (j ^ m)] * kk;  // hi lane: input chain
            WP[g][m] = w;
        }
        f32x2 gb; gb.x = (b_ih[row] + b_hh[row]) * kk; gb.y = 0.0f;
        GbP[g] = gb;
    }
    const float regw = reg_w[j];
    const float regb = reg_b[0];
    const int bpaddr = ((lane >= 8) ? (lane - 8) : (lane + 56)) << 2;

    float h = 0.0f, c = 0.0f;
    float bufA[CH], bufB[CH], su[CH];
    uint32_t wi = (uint32_t)(b * 4 + j);         // running word offset into x
#pragma unroll
    for (int u = 0; u < CH; ++u) { bufA[u] = x[wi]; wi += 4096; }   // t=0..15

// PREFM_: 0=no prefetch, 1=stream next 16 t's, 2=clamped (replicate t=2047)
#define RUN_CHUNK(cc_, cur_, nxt_, MASKF_, PREFM_, GUARDF_, NSTEPS_) do {      \
    if ((PREFM_) == 1) {                                                       \
        _Pragma("unroll")                                                      \
        for (int u = 0; u < CH; ++u) { nxt_[u] = x[wi]; wi += 4096; }          \
    } else if ((PREFM_) == 2) {                                                \
        const float xl = x[2047u * 4096u + (uint32_t)(b * 4 + j)];             \
        _Pragma("unroll")                                                      \
        for (int u = 0; u < CH; ++u) nxt_[u] = xl;                             \
    }                                                                          \
    _Pragma("unroll")                                                          \
    for (int u = 0; u < (NSTEPS_); ++u) {                                      \
        const float hsrc = isFeeder ? cur_[u] : h;   /* feeders publish x */   \
        const float hup  = bpermf(bpaddr, hsrc);     /* h from layer above */  \
        const float hv1 = dppf<0xB1>(h),   hv2 = dppf<0x4E>(h),                \
                    hv3 = dppf<0x1B>(h);                                       \
        const float xv1 = dppf<0xB1>(hup), xv2 = dppf<0x4E>(hup),              \
                    xv3 = dppf<0x1B>(hup);                                     \
        f32x2 V0, V1, V2, V3;                                                  \
        V0.x = h;   V0.y = hup;                                                \
        V1.x = hv1; V1.y = xv1;                                                \
        V2.x = hv2; V2.y = xv2;                                                \
        V3.x = hv3; V3.y = xv3;                                                \
        f32x2 Ai = pkfma(WP[0][0], V0, GbP[0]);                                \
        f32x2 Af = pkfma(WP[1][0], V0, GbP[1]);                                \
        f32x2 Ag = pkfma(WP[2][0], V0, GbP[2]);                                \
        f32x2 Ao = pkfma(WP[3][0], V0, GbP[3]);                                \
        Ai = pkfma(WP[0][1], V1, Ai); Af = pkfma(WP[1][1], V1, Af);            \
        Ag = pkfma(WP[2][1], V1, Ag); Ao = pkfma(WP[3][1], V1, Ao);            \
        Ai = pkfma(WP[0][2], V2, Ai); Af = pkfma(WP[1][2], V2, Af);            \
        Ag = pkfma(WP[2][2], V2, Ag); Ao = pkfma(WP[3][2], V2, Ao);            \
        Ai = pkfma(WP[0][3], V3, Ai); Af = pkfma(WP[1][3], V3, Af);            \
        Ag = pkfma(WP[2][3], V3, Ag); Ao = pkfma(WP[3][3], V3, Ao);            \
        const float si = frcp(1.0f + fexp2(Ai.x + Ai.y));                      \
        const float sf = frcp(1.0f + fexp2(Af.x + Af.y));                      \
        const float tg = fmaf(2.0f, frcp(1.0f + fexp2(Ag.x + Ag.y)), -1.0f);   \
        const float so = frcp(1.0f + fexp2(Ao.x + Ao.y));                      \
        const float cn = fmaf(sf, c, si * tg);                                 \
        const float th = fmaf(2.0f, frcp(1.0f + fexp2(cn * KGc)), -1.0f);      \
        const float hn = so * th;                                              \
        if (MASKF_) {                                                          \
            const bool act = (u >= L);               /* pipeline-fill gate */  \
            c = act ? cn : c;                                                  \
            h = act ? hn : h;                                                  \
        } else { c = cn; h = hn; }                                             \
        float s = h * regw;                          /* linear head */         \
        s += dppf<0xB1>(s);                                                    \
        s += dppf<0x4E>(s);                                                    \
        su[u] = s + regb;                                                      \
    }                                                                          \
    if (isOut) {                                                               \
        const int base = (cc_) * CH - (NL - 1);                                \
        _Pragma("unroll")                                                      \
        for (int u = 0; u < (NSTEPS_); ++u) {                                  \
            const int t = base + u;                                            \
            if (!(GUARDF_) || ((t >= 0) && (t < S_LEN)))                       \
                out[(size_t)t * BATCH + b] = su[u];                            \
        }                                                                      \
    }                                                                          \
} while (0)

    // chunk 0: masked (pipeline fill), prefetch t=16..31 into bufB
    RUN_CHUNK(0, bufA, bufB, 1, 1, 1, CH);
    // bulk: chunks 1..126, maskless, guardless, ping-pong buffers
#pragma unroll 1
    for (int cc = 1; cc < 127; cc += 2) {
        RUN_CHUNK(cc,     bufB, bufA, 0, 1, 0, CH);
        RUN_CHUNK(cc + 1, bufA, bufB, 0, 1, 0, CH);
    }
    // chunk 127: last real x tile; clamped prefetch (t=2047 replicated)
    RUN_CHUNK(127, bufB, bufA, 0, 2, 0, CH);
    // chunk 128: 5 drain steps produce t=2043..2047 on L5
    RUN_CHUNK(128, bufA, bufB, 0, 0, 0, 5);
#undef RUN_CHUNK
}

extern "C" void kernel_launch(void* const* d_in, const int* in_sizes, int n_in,
                              void* d_out, int out_size, void* d_ws, size_t ws_size,
                              hipStream_t stream) {
    const float* x     = (const float*)d_in[0];
    const float* w_ih  = (const float*)d_in[1];
    const float* w_hh  = (const float*)d_in[2];
    const float* b_ih  = (const float*)d_in[3];
    const float* b_hh  = (const float*)d_in[4];
    const float* reg_w = (const float*)d_in[5];
    const float* reg_b = (const float*)d_in[6];
    float* out = (float*)d_out;

    dim3 grid(BATCH / 2);   // 512 single-wave blocks, 2 batch elements each
    dim3 block(64);
    hipLaunchKernelGGL(lstm_wavepipe, grid, block, 0, stream, x, w_ih, w_hh,
                       b_ih, b_hh, reg_w, reg_b, out);
}